// Round 1
// baseline (124.357 us; speedup 1.0000x reference)
//
#include <hip/hip_runtime.h>

#define DIM 16
#define SEQ 2048

// ---------------- quantum circuit primitives (all register-resident) --------

template<int P>
__device__ __forceinline__ void rx_bit(float sr[DIM], float si[DIM], float ch, float sh) {
    // RX on bit position P: new0 = c*a0 - i*s*a1 ; new1 = c*a1 - i*s*a0
    constexpr int m = 1 << P;
    #pragma unroll
    for (int i = 0; i < DIM; ++i) {
        if ((i & m) == 0) {
            const int j = i | m;
            float r0 = sr[i], i0 = si[i], r1 = sr[j], i1 = si[j];
            sr[i] = fmaf(ch, r0,  sh * i1);
            si[i] = fmaf(ch, i0, -sh * r1);
            sr[j] = fmaf(ch, r1,  sh * i0);
            si[j] = fmaf(ch, i1, -sh * r0);
        }
    }
}

template<int PC, int PT>
__device__ __forceinline__ void cnot_g(float sr[DIM], float si[DIM]) {
    constexpr int cm = 1 << PC, tm = 1 << PT;
    #pragma unroll
    for (int i = 0; i < DIM; ++i) {
        if ((i & cm) && !(i & tm)) {
            const int j = i | tm;
            float t;
            t = sr[i]; sr[i] = sr[j]; sr[j] = t;
            t = si[i]; si[i] = si[j]; si[j] = t;
        }
    }
}

__device__ __forceinline__ void embed(float sr[DIM], float si[DIM], float4 a) {
    #pragma unroll
    for (int i = 0; i < DIM; ++i) { sr[i] = 0.f; si[i] = 0.f; }
    sr[0] = 1.f;
    float ch, sh;
    __sincosf(0.5f * a.x, &sh, &ch); rx_bit<3>(sr, si, ch, sh);   // wire 0 -> bit 3
    __sincosf(0.5f * a.y, &sh, &ch); rx_bit<2>(sr, si, ch, sh);
    __sincosf(0.5f * a.z, &sh, &ch); rx_bit<1>(sr, si, ch, sh);
    __sincosf(0.5f * a.w, &sh, &ch); rx_bit<0>(sr, si, ch, sh);
}

__device__ __forceinline__ void layer(float sr[DIM], float si[DIM], float4 w) {
    float ch, sh;
    __sincosf(0.5f * w.x, &sh, &ch); rx_bit<3>(sr, si, ch, sh);
    __sincosf(0.5f * w.y, &sh, &ch); rx_bit<2>(sr, si, ch, sh);
    __sincosf(0.5f * w.z, &sh, &ch); rx_bit<1>(sr, si, ch, sh);
    __sincosf(0.5f * w.w, &sh, &ch); rx_bit<0>(sr, si, ch, sh);
    // CNOT ring: (c=0,t=1)->(bits 3,2), (1,2)->(2,1), (2,3)->(1,0), (3,0)->(0,3)
    cnot_g<3,2>(sr, si);
    cnot_g<2,1>(sr, si);
    cnot_g<1,0>(sr, si);
    cnot_g<0,3>(sr, si);
}

__device__ __forceinline__ float4 measure(const float sr[DIM], const float si[DIM]) {
    float e0 = 0.f, e1 = 0.f, e2 = 0.f, e3 = 0.f;
    #pragma unroll
    for (int i = 0; i < DIM; ++i) {
        float p = fmaf(sr[i], sr[i], si[i] * si[i]);
        e0 += (i & 8) ? -p : p;   // wire 0 -> bit 3
        e1 += (i & 4) ? -p : p;
        e2 += (i & 2) ? -p : p;
        e3 += (i & 1) ? -p : p;
    }
    return make_float4(e0, e1, e2, e3);
}

// ---------------- kernel 1: Q,K,V circuits --------------------------------

__global__ __launch_bounds__(256) void qkv_kernel(
        const float* __restrict__ x,
        const float* __restrict__ wQp, const float* __restrict__ wKp,
        const float* __restrict__ wVp,
        float4* __restrict__ Q, float4* __restrict__ K, float4* __restrict__ V) {
    const int i = blockIdx.x * 256 + threadIdx.x;
    const float4 xv = ((const float4*)x)[i];
    const float4 wQ = *(const float4*)wQp;
    const float4 wK = *(const float4*)wKp;
    const float4 wV = *(const float4*)wVp;

    float sr[DIM], si[DIM];
    embed(sr, si, xv);              // shared embedding state for Q,K,V

    float tr[DIM], ti[DIM];
    #pragma unroll
    for (int k = 0; k < DIM; ++k) { tr[k] = sr[k]; ti[k] = si[k]; }
    layer(tr, ti, wQ);
    Q[i] = measure(tr, ti);

    #pragma unroll
    for (int k = 0; k < DIM; ++k) { tr[k] = sr[k]; ti[k] = si[k]; }
    layer(tr, ti, wK);
    K[i] = measure(tr, ti);

    layer(sr, si, wV);
    V[i] = measure(sr, si);
}

// ---------------- kernel 2: attention + final circuit ---------------------

__global__ __launch_bounds__(256) void attn_kernel(
        const float4* __restrict__ Q, const float4* __restrict__ K,
        const float4* __restrict__ V, const float* __restrict__ wCp,
        float4* __restrict__ out) {
    __shared__ float4 Ks[SEQ];
    __shared__ float4 Vs[SEQ];

    const int b  = blockIdx.x >> 3;     // 8 row-blocks per batch
    const int rb = blockIdx.x & 7;

    const float4* Kb = K + b * SEQ;
    const float4* Vb = V + b * SEQ;
    for (int t = threadIdx.x; t < SEQ; t += 256) {
        Ks[t] = Kb[t];
        Vs[t] = Vb[t];
    }
    __syncthreads();

    const int row = b * SEQ + rb * 256 + threadIdx.x;
    const float4 q = Q[row];
    // fold the 1/sqrt(E)=0.5 scale into q once
    const float qx = q.x * 0.5f, qy = q.y * 0.5f, qz = q.z * 0.5f, qw = q.w * 0.5f;

    // scores in [-2,2]  =>  exp never overflows: no running-max needed
    float den = 0.f, a0 = 0.f, a1 = 0.f, a2 = 0.f, a3 = 0.f;
    #pragma unroll 8
    for (int k = 0; k < SEQ; ++k) {
        const float4 kv = Ks[k];   // wave-uniform address -> LDS broadcast
        float s = fmaf(qx, kv.x, fmaf(qy, kv.y, fmaf(qz, kv.z, qw * kv.w)));
        float e = __expf(s);
        const float4 vv = Vs[k];
        den += e;
        a0 = fmaf(e, vv.x, a0);
        a1 = fmaf(e, vv.y, a1);
        a2 = fmaf(e, vv.z, a2);
        a3 = fmaf(e, vv.w, a3);
    }
    const float inv = 1.0f / den;
    const float4 ctx = make_float4(a0 * inv, a1 * inv, a2 * inv, a3 * inv);

    // fused final circuit on ctx with weights_C
    const float4 wC = *(const float4*)wCp;
    float sr[DIM], si[DIM];
    embed(sr, si, ctx);
    layer(sr, si, wC);
    out[row] = measure(sr, si);
}

// ---------------- launch ---------------------------------------------------

extern "C" void kernel_launch(void* const* d_in, const int* in_sizes, int n_in,
                              void* d_out, int out_size, void* d_ws, size_t ws_size,
                              hipStream_t stream) {
    const float* x  = (const float*)d_in[0];
    const float* wQ = (const float*)d_in[1];
    const float* wK = (const float*)d_in[2];
    const float* wV = (const float*)d_in[3];
    const float* wC = (const float*)d_in[4];

    const int n = in_sizes[0] / 4;          // B*S = 65536 elements
    float4* Q = (float4*)d_ws;              // n float4  = 1 MB
    float4* K = Q + n;                      // n float4  = 1 MB
    float4* V = K + n;                      // n float4  = 1 MB

    qkv_kernel<<<n / 256, 256, 0, stream>>>(x, wQ, wK, wV, Q, K, V);

    const int batches = n / SEQ;            // 32
    attn_kernel<<<batches * 8, 256, 0, stream>>>(Q, K, V, wC, (float4*)d_out);
}